// Round 14
// baseline (1430.740 us; speedup 1.0000x reference)
//
#include <hip/hip_runtime.h>
#include <hip/hip_bf16.h>

#define NN 50000
#define DEG 16

typedef __attribute__((ext_vector_type(8))) short bfrag;   // 8 x bf16 bits (16B)
typedef __attribute__((ext_vector_type(4))) float f32x4;

__device__ __forceinline__ float bf2f(unsigned int u){ return __uint_as_float(u<<16); }
__device__ __forceinline__ unsigned short f2bf(float x){
  unsigned int u = __float_as_uint(x);
  unsigned int r = (u + 0x7fffu + ((u>>16)&1u)) >> 16;
  return (unsigned short)r;
}
__device__ __forceinline__ float fast_rcp(float x){ return __builtin_amdgcn_rcpf(x); }
__device__ __forceinline__ float sigmoidf_(float x){ return fast_rcp(1.f + __expf(-x)); }
__device__ __forceinline__ float tanh_fast(float x){
  float e = __expf(-2.f*fabsf(x));
  float r = (1.f - e)*fast_rcp(1.f + e);
  return copysignf(r, x);
}

#define SWZ(row) (((((row) ^ ((row)>>3)) & 7)) << 4)
// 4-bit slot swizzle for 256B rows (16 x 16B slots): final_slot = slot ^ (row&15)
#define SW4(row) (((row) & 15) << 4)

// global->LDS DMA, 16B per lane; LDS dest is wave-uniform base + lane*16 (linear).
#define GLDS16(g, l) __builtin_amdgcn_global_load_lds( \
    (const __attribute__((address_space(1))) unsigned int*)(g), \
    (__attribute__((address_space(3))) unsigned int*)(l), 16, 0, 0)

__global__ void k_cvt(const float* __restrict__ in, unsigned short* __restrict__ out, int n){
  int i = blockIdx.x*256 + threadIdx.x;
  if (i < n) out[i] = f2bf(in[i]);
}

// ONE prep kernel. Wpck packs [Wih|Whh] rows so each 16-row M-tile holds
// TWO gates x 8 hidden units: prow p -> wave w=p>>5, tile=(p>>4)&1, lr=p&15,
// gate T=tile*2+(lr>=8), hidden u=w*8+(lr&7), orig row R=T*128+u.
__global__ void k_prep_all(const float* __restrict__ Wih, const float* __restrict__ Whh,
                           const float* __restrict__ bih, const float* __restrict__ bhh,
                           const float* __restrict__ WlL, const float* __restrict__ WrL,
                           const float* __restrict__ W1,  const float* __restrict__ W2,
                           const float* __restrict__ W3,
                           unsigned short* __restrict__ Wpck, float* __restrict__ bspck,
                           unsigned short* __restrict__ Wlb,  unsigned short* __restrict__ Wrb,
                           unsigned short* __restrict__ W1nb,
                           unsigned short* __restrict__ W1eh, unsigned short* __restrict__ W1el,
                           unsigned short* __restrict__ W2h,  unsigned short* __restrict__ W2l,
                           unsigned short* __restrict__ W3p)
{
  int i = blockIdx.x*256 + threadIdx.x;
  if (i < 393216){                       // Wpck[l][512][256] packed
    int lidx = i >> 17;
    int rem = i & 131071;
    int p = rem >> 8, col = rem & 255;
    int wv = p >> 5, tl = (p >> 4) & 1, lr = p & 15;
    int T = tl*2 + (lr >> 3), u = wv*8 + (lr & 7);
    int R = T*128 + u;
    float v = (col < 128) ? Wih[((size_t)lidx*512 + R)*128 + col]
                          : Whh[((size_t)lidx*512 + R)*128 + (col-128)];
    Wpck[i] = f2bf(v);
  } else if (i < 394752){                // bspck = (bih+bhh) packed
    int k = i - 393216;
    int lidx = k >> 9; int p = k & 511;
    int wv = p >> 5, tl = (p >> 4) & 1, lr = p & 15;
    int T = tl*2 + (lr >> 3), u = wv*8 + (lr & 7);
    int R = T*128 + u;
    bspck[k] = bih[(size_t)lidx*512 + R] + bhh[(size_t)lidx*512 + R];
  } else if (i < 443904){                // Wlb
    int k = i - 394752;
    Wlb[k] = f2bf(WlL[k]);
  } else if (i < 493056){                // Wrb
    int k = i - 443904;
    Wrb[k] = f2bf(WrL[k]);
  } else if (i < 509440){                // W1nb rows 0..127 = W1[:, :128]
    int k = i - 493056; int r = k >> 7, c = k & 127;
    W1nb[k] = f2bf(W1[(size_t)r*272 + c]);
  } else if (i < 525824){                // W1nb rows 128..255 = W1[:, 128:256]
    int k = i - 509440; int r = k >> 7, c = k & 127;
    W1nb[16384 + k] = f2bf(W1[(size_t)r*272 + 128 + c]);
  } else if (i < 534016){                // W2 hi/lo
    int k = i - 525824;
    float v = W2[k];
    unsigned short hi = f2bf(v);
    W2h[k] = hi; W2l[k] = f2bf(v - bf2f(hi));
  } else if (i < 536064){                // W1e hi/lo (transposed [128][16])
    int k = i - 534016; int j = k >> 4, kk = k & 15;
    float v = W1[(size_t)j*272 + 256 + kk];
    unsigned short hi = f2bf(v);
    W1eh[k] = hi; W1el[k] = f2bf(v - bf2f(hi));
  } else if (i < 537088){                // W3 zero-padded [16][64]
    int k = i - 536064; int nr = k >> 6, c = k & 63;
    W3p[k] = f2bf(nr < 2 ? W3[nr*64 + c] : 0.f);
  }
}

// bf16 MFMA gemm (HsHd precompute, bf16 out). Unchanged.
__global__ __launch_bounds__(256,4) void k_bgemm(
    const unsigned short* __restrict__ Ab, const unsigned short* __restrict__ A2b,
    const unsigned short* __restrict__ Wb, const unsigned short* __restrict__ W2b,
    const float* __restrict__ bias, const float* __restrict__ bias2,
    float* __restrict__ outF, unsigned short* __restrict__ outB,
    int ostride, int dorelu, int n)
{
  const int t  = threadIdx.x;
  const int w  = t >> 6;
  const int l  = t & 63;
  const int ln = l & 15, q = l >> 4;
  const int n0 = blockIdx.x*64;
  const int j0 = blockIdx.y*128 + w*32;

  int nodeM[4];
#pragma unroll
  for (int mt=0;mt<4;mt++){ int nd = n0 + mt*16 + ln; nodeM[mt] = nd < n ? nd : n-1; }

  f32x4 acc[4][2];
#pragma unroll
  for (int mt=0;mt<4;mt++)
#pragma unroll
    for (int nt=0;nt<2;nt++) acc[mt][nt] = (f32x4){0.f,0.f,0.f,0.f};

  auto pass = [&](const unsigned short* __restrict__ Ap, const unsigned short* __restrict__ Wp){
#pragma unroll
    for (int ks=0;ks<4;ks++){
      bfrag Af[4], Bf[2];
#pragma unroll
      for (int mt=0;mt<4;mt++)
        Af[mt] = *(const bfrag*)(Ap + (size_t)nodeM[mt]*128 + ks*32 + q*8);
#pragma unroll
      for (int nt=0;nt<2;nt++)
        Bf[nt] = *(const bfrag*)(Wp + (size_t)(j0 + nt*16 + ln)*128 + ks*32 + q*8);
#pragma unroll
      for (int mt=0;mt<4;mt++)
#pragma unroll
        for (int nt=0;nt<2;nt++)
          acc[mt][nt] = __builtin_amdgcn_mfma_f32_16x16x32_bf16(Af[mt], Bf[nt], acc[mt][nt], 0,0,0);
    }
  };
  pass(Ab, Wb);
  if (A2b) pass(A2b, W2b);

#pragma unroll
  for (int nt=0;nt<2;nt++){
    int j = j0 + nt*16 + ln;
    float bv = bias ? bias[j] : 0.f;
    if (bias2) bv += bias2[j];
#pragma unroll
    for (int mt=0;mt<4;mt++)
#pragma unroll
      for (int r=0;r<4;r++){
        int row = n0 + mt*16 + q*4 + r;
        if (row < n){
          float v = acc[mt][nt][r] + bv;
          if (dorelu) v = fmaxf(v, 0.f);
          if (outF) outF[(size_t)row*ostride + j] = v;
          if (outB) outB[(size_t)row*ostride + j] = f2bf(v);
        }
      }
  }
}

// MFMA LSTM v12: 1024 thr (16 waves), gate-pair-packed weights -> A-frags 64 VGPR,
// <=128 total regs -> 4 waves/SIMD (2x occupancy vs v9). Cross-half gate exchange
// via shfl_xor(32) with r-range split (no duplicated activation work).
// h double-buffered: ONE barrier per step. Fused lin_l/lin_r epilogue (16 waves).
__global__ __launch_bounds__(1024, 4) void k_lstm12(
    const unsigned short* __restrict__ xin,  // [n][128] bf16 layer input
    const int* __restrict__ src,             // [n*16]
    const unsigned short* __restrict__ Wpck, // [512][256] bf16 packed
    const float* __restrict__ bspck,         // [512] packed biases
    const unsigned short* __restrict__ Wlb,  // [128][128] bf16 lin_l
    const unsigned short* __restrict__ Wrb,  // [128][128] bf16 lin_r
    const float* __restrict__ bl,            // [128]
    unsigned short* __restrict__ hout,       // [n][128] bf16 layer output
    int n)
{
  __shared__ unsigned short hs[2][64*128];     // 2 x 16 KB, row=node (256B), SW4
  __shared__ unsigned short xbuf[2][64*128];   // 2 x 16 KB, SW4
  __shared__ int srcs[1024];
  const int t  = threadIdx.x;
  const int w  = t >> 6;                       // 0..15
  const int l  = t & 63;
  const int ln = l & 15;
  const int q  = l >> 4;
  const int n0 = blockIdx.x * 64;

  { int nl = t >> 4, st = t & 15;
    srcs[t] = (n0+nl < n) ? src[(size_t)(n0+nl)*16 + st] : 0; }

  // A-frags: wave w owns M-tiles [g0|g1] and [g2|g3] for hidden slice [w*8, w*8+8)
  bfrag A[2][8];
#pragma unroll
  for (int tl=0; tl<2; tl++)
#pragma unroll
    for (int ks=0; ks<8; ks++)
      A[tl][ks] = *(const bfrag*)(Wpck + (size_t)(w*32 + tl*16 + ln)*256 + ks*32 + q*8);

  // biases (packed rows match D rows). Partner (lane^32) holds complementary gates.
  f32x4 bs0 = *(const f32x4*)(bspck + w*32 + q*4);
  f32x4 bs1 = *(const f32x4*)(bspck + w*32 + 16 + q*4);
  f32x4 ob0, ob1;
#pragma unroll
  for (int i=0;i<4;i++){
    ob0[i] = __shfl_xor(bs0[i], 32, 64);
    ob1[i] = __shfl_xor(bs1[i], 32, 64);
  }
  const bool lo = (q < 2);
  float bI[2], bF[2], bG[2], bO[2];
#pragma unroll
  for (int rr=0; rr<2; rr++){
    float a0 = lo ? bs0[rr] : bs0[2+rr];
    float p0 = lo ? ob0[rr] : ob0[2+rr];
    float a1 = lo ? bs1[rr] : bs1[2+rr];
    float p1 = lo ? ob1[rr] : ob1[2+rr];
    bI[rr] = lo ? a0 : p0;
    bF[rr] = lo ? p0 : a0;
    bG[rr] = lo ? a1 : p1;
    bO[rr] = lo ? p1 : a1;
  }

  float c[4][2];   // [nt][rr] cell state for this thread's 2 r's
#pragma unroll
  for (int nt=0;nt<4;nt++){ c[nt][0]=0.f; c[nt][1]=0.f; }

  __syncthreads();   // srcs visible

  // DMA one step's 64 x-rows: wave w loads rows [w*4, w*4+4) in ONE instr.
  auto stageX = [&](int step, int buf){
    int row  = w*4 + (l>>4);
    int node = srcs[row*16 + step];
    const char* gsrc = (const char*)xin + (size_t)node*256 + (((l&15)*16) ^ SW4(row));
    char* ldst = (char*)&xbuf[buf][0] + (w*4)*256;   // wave-uniform base
    GLDS16(gsrc, ldst);
  };

  stageX(0, 0);
  asm volatile("s_waitcnt vmcnt(0)" ::: "memory");
  __syncthreads();

  const int hwoff = w*16 + (q&1)*8 + (q>>1)*4;   // byte offset of this thread's h pair

  for (int step=0; step<16; step++){
    const int xcur = step & 1;
    const int hrb  = step & 1;       // read buffer (valid step>0)
    const int hwb  = hrb ^ 1;        // write buffer
    if (step < 15) stageX(step+1, xcur^1);

#pragma unroll
    for (int nt=0; nt<4; nt++){
      int node = nt*16 + ln;
      int swz  = SW4(node);
      f32x4 acc0 = (f32x4){0.f,0.f,0.f,0.f};
      f32x4 acc1 = (f32x4){0.f,0.f,0.f,0.f};
#pragma unroll
      for (int ks=0;ks<4;ks++){
        bfrag Bk = *(const bfrag*)((const char*)&xbuf[xcur][0] + node*256 +
                     ((ks*64 + q*16) ^ swz));
        acc0 = __builtin_amdgcn_mfma_f32_16x16x32_bf16(A[0][ks], Bk, acc0, 0,0,0);
        acc1 = __builtin_amdgcn_mfma_f32_16x16x32_bf16(A[1][ks], Bk, acc1, 0,0,0);
      }
      if (step > 0){
#pragma unroll
        for (int ks=4;ks<8;ks++){
          bfrag Bk = *(const bfrag*)((const char*)&hs[hrb][0] + node*256 +
                       (((ks-4)*64 + q*16) ^ swz));
          acc0 = __builtin_amdgcn_mfma_f32_16x16x32_bf16(A[0][ks], Bk, acc0, 0,0,0);
          acc1 = __builtin_amdgcn_mfma_f32_16x16x32_bf16(A[1][ks], Bk, acc1, 0,0,0);
        }
      }
      // cross-half exchange: partner holds the other two gates for same (node,u)
      f32x4 o0, o1;
#pragma unroll
      for (int i=0;i<4;i++){
        o0[i] = __shfl_xor(acc0[i], 32, 64);
        o1[i] = __shfl_xor(acc1[i], 32, 64);
      }
      float h2[2];
#pragma unroll
      for (int rr=0; rr<2; rr++){
        float a0 = lo ? acc0[rr] : acc0[2+rr];
        float p0 = lo ? o0[rr]   : o0[2+rr];
        float a1 = lo ? acc1[rr] : acc1[2+rr];
        float p1 = lo ? o1[rr]   : o1[2+rr];
        float iv = (lo ? a0 : p0) + bI[rr];
        float fv = (lo ? p0 : a0) + bF[rr];
        float gg = (lo ? a1 : p1) + bG[rr];
        float ov = (lo ? p1 : a1) + bO[rr];
        float cn = sigmoidf_(fv)*c[nt][rr] + sigmoidf_(iv)*tanh_fast(gg);
        c[nt][rr] = cn;
        h2[rr] = sigmoidf_(ov)*tanh_fast(cn);
      }
      unsigned pk;
      asm("v_cvt_pk_bf16_f32 %0, %1, %2" : "=v"(pk) : "v"(h2[0]), "v"(h2[1]));
      *(unsigned*)((char*)&hs[hwb][0] + node*256 + (hwoff ^ swz)) = pk;
    }
    asm volatile("s_waitcnt vmcnt(0)" ::: "memory");  // next-step xbuf landed
    __syncthreads();   // h writes + xbuf visible for next step
  }

  // ---- fused epilogue: hout = relu(Wl·h + Wr·x_own + bl); final h in hs[0].
  // 16 waves: wave handles j-tile (w&7) for node half (w>>3).
  {
    const int jw  = w & 7;
    const int ntb = (w >> 3) * 2;
    bfrag Al[4], Ar[4];
#pragma unroll
    for (int ks=0;ks<4;ks++){
      Al[ks] = *(const bfrag*)(Wlb + (size_t)(jw*16+ln)*128 + ks*32 + q*8);
      Ar[ks] = *(const bfrag*)(Wrb + (size_t)(jw*16+ln)*128 + ks*32 + q*8);
    }
    f32x4 blv = *(const f32x4*)(bl + jw*16 + q*4);
#pragma unroll
    for (int nn=0; nn<2; nn++){
      int nt = ntb + nn;
      int node = nt*16 + ln;
      int gn = (n0+node < n) ? (n0+node) : (n-1);
      f32x4 acc = (f32x4){0.f,0.f,0.f,0.f};
#pragma unroll
      for (int ks=0;ks<4;ks++){
        bfrag Bh = *(const bfrag*)((const char*)&hs[0][0] + node*256 +
                     ((ks*64 + q*16) ^ SW4(node)));
        bfrag Bx = *(const bfrag*)(xin + (size_t)gn*128 + ks*32 + q*8);
        acc = __builtin_amdgcn_mfma_f32_16x16x32_bf16(Al[ks], Bh, acc, 0,0,0);
        acc = __builtin_amdgcn_mfma_f32_16x16x32_bf16(Ar[ks], Bx, acc, 0,0,0);
      }
      float v0 = fmaxf(acc[0]+blv[0], 0.f), v1 = fmaxf(acc[1]+blv[1], 0.f);
      float v2 = fmaxf(acc[2]+blv[2], 0.f), v3 = fmaxf(acc[3]+blv[3], 0.f);
      unsigned pk01, pk23;
      asm("v_cvt_pk_bf16_f32 %0, %1, %2" : "=v"(pk01) : "v"(v0), "v"(v1));
      asm("v_cvt_pk_bf16_f32 %0, %1, %2" : "=v"(pk23) : "v"(v2), "v"(v3));
      if (n0+node < n){
        uint2 pv; pv.x = pk01; pv.y = pk23;
        *(uint2*)(hout + (size_t)(n0+node)*128 + jw*16 + q*4) = pv;
      }
    }
  }
}

// Edge MLP v4: Hs/Hd gathered as BF16. Unchanged from R13.
__global__ __launch_bounds__(256,2) void k_edge4(
    const unsigned short* __restrict__ HsHd,
    const float* __restrict__ ea,
    const int* __restrict__ src,
    const unsigned short* __restrict__ W1eh, const unsigned short* __restrict__ W1el,
    const unsigned short* __restrict__ W2h,  const unsigned short* __restrict__ W2l,
    const unsigned short* __restrict__ W3p,
    const float* __restrict__ b1, const float* __restrict__ b2, const float* __restrict__ b3,
    float* __restrict__ out)
{
  __shared__ unsigned short out1h[64*128];
  __shared__ unsigned short out1l[64*128];
  __shared__ unsigned short e2h[64*64];
  __shared__ unsigned short e2l[64*64];
  __shared__ unsigned short ea2[64*56];

  const int t = threadIdx.x;
  const int w = t>>6, l = t&63, ln = l&15, q = l>>4;
  const int nblk = blockIdx.x;
  const size_t e0 = (size_t)nblk*64;

  int srcv[4];
#pragma unroll
  for (int r=0;r<4;r++) srcv[r] = src[e0 + w*16 + q*4 + r];

  unsigned short hsq[8][4];
#pragma unroll
  for (int nt=0;nt<8;nt++)
#pragma unroll
    for (int r=0;r<4;r++)
      hsq[nt][r] = HsHd[(size_t)srcv[r]*256 + nt*16 + ln];

  unsigned short hdq[8];
#pragma unroll
  for (int nt=0;nt<8;nt++)
    hdq[nt] = HsHd[((size_t)nblk*4 + w)*256 + 128 + nt*16 + ln];

  float b1v[8];
#pragma unroll
  for (int nt=0;nt<8;nt++) b1v[nt] = b1[nt*16 + ln];
  float b2v[4];
#pragma unroll
  for (int nt=0;nt<4;nt++) b2v[nt] = b2[nt*16 + ln];
  float b3v = (ln<2) ? b3[ln] : 0.f;

  bfrag w1h[8], w1l[8];
#pragma unroll
  for (int nt=0;nt<8;nt++){
    int j = nt*16 + ln;
    w1h[nt] = *(const bfrag*)(W1eh + (size_t)j*16 + (q&1)*8);
    w1l[nt] = *(const bfrag*)(W1el + (size_t)j*16 + (q&1)*8);
  }
  bfrag w3f[2];
#pragma unroll
  for (int ks=0;ks<2;ks++)
    w3f[ks] = *(const bfrag*)(W3p + (size_t)ln*64 + ks*32 + q*8);

  for (int i=t;i<1024;i+=256){
    int e=i>>4, k=i&15;
    float v = ea[(e0+e)*16 + k];
    unsigned short hi = f2bf(v);
    ea2[e*56 + k] = hi;
    ea2[e*56 + 16 + k] = f2bf(v - bf2f(hi));
  }
  __syncthreads();

  {
    bfrag Aea = *(const bfrag*)&ea2[(w*16+ln)*56 + q*8];
#pragma unroll
    for (int nt=0;nt<8;nt++){
      float hdv = bf2f((unsigned)hdq[nt]);
      f32x4 acc;
#pragma unroll
      for (int r=0;r<4;r++) acc[r] = b1v[nt] + hdv + bf2f((unsigned)hsq[nt][r]);
      acc = __builtin_amdgcn_mfma_f32_16x16x32_bf16(Aea, w1h[nt], acc, 0,0,0);
      acc = __builtin_amdgcn_mfma_f32_16x16x32_bf16(Aea, w1l[nt], acc, 0,0,0);
      int j = nt*16 + ln;
#pragma unroll
      for (int r=0;r<4;r++){
        int row = w*16 + q*4 + r;
        float v = fmaxf(acc[r], 0.f);
        unsigned short hi = f2bf(v);
        float lov = v - bf2f(hi);
        int byt = row*256 + ((j*2) ^ SWZ(row));
        *(unsigned short*)((char*)out1h + byt) = hi;
        *(unsigned short*)((char*)out1l + byt) = f2bf(lov);
      }
    }
  }
  __syncthreads();

  {
    f32x4 acc[4];
#pragma unroll
    for (int nt=0;nt<4;nt++) acc[nt] = (f32x4){b2v[nt],b2v[nt],b2v[nt],b2v[nt]};
    int arow = w*16 + ln;

    bfrag BhA[4], BlA[4], BhB[4], BlB[4];
#pragma unroll
    for (int nt=0;nt<4;nt++){
      int j = nt*16 + ln;
      BhA[nt] = *(const bfrag*)(W2h + (size_t)j*128 + q*8);
      BlA[nt] = *(const bfrag*)(W2l + (size_t)j*128 + q*8);
    }
#pragma unroll
    for (int ks=0;ks<4;ks++){
      if (ks < 3){
#pragma unroll
        for (int nt=0;nt<4;nt++){
          int j = nt*16 + ln;
          if ((ks&1)==0){
            BhB[nt] = *(const bfrag*)(W2h + (size_t)j*128 + (ks+1)*32 + q*8);
            BlB[nt] = *(const bfrag*)(W2l + (size_t)j*128 + (ks+1)*32 + q*8);
          } else {
            BhA[nt] = *(const bfrag*)(W2h + (size_t)j*128 + (ks+1)*32 + q*8);
            BlA[nt] = *(const bfrag*)(W2l + (size_t)j*128 + (ks+1)*32 + q*8);
          }
        }
      }
      int byt = arow*256 + ((ks*64 + q*16) ^ SWZ(arow));
      bfrag Ah = *(const bfrag*)((char*)out1h + byt);
      bfrag Al = *(const bfrag*)((char*)out1l + byt);
#pragma unroll
      for (int nt=0;nt<4;nt++){
        bfrag Bh = ((ks&1)==0) ? BhA[nt] : BhB[nt];
        bfrag Bl = ((ks&1)==0) ? BlA[nt] : BlB[nt];
        acc[nt] = __builtin_amdgcn_mfma_f32_16x16x32_bf16(Ah, Bh, acc[nt], 0,0,0);
        acc[nt] = __builtin_amdgcn_mfma_f32_16x16x32_bf16(Al, Bh, acc[nt], 0,0,0);
        acc[nt] = __builtin_amdgcn_mfma_f32_16x16x32_bf16(Ah, Bl, acc[nt], 0,0,0);
      }
    }
#pragma unroll
    for (int nt=0;nt<4;nt++)
#pragma unroll
      for (int r=0;r<4;r++){
        int row = w*16 + q*4 + r;
        int j = nt*16 + ln;
        float v = fmaxf(acc[nt][r], 0.f);
        unsigned short hi = f2bf(v);
        float lov = v - bf2f(hi);
        int byt = row*128 + ((j*2) ^ SWZ(row));
        *(unsigned short*)((char*)e2h + byt) = hi;
        *(unsigned short*)((char*)e2l + byt) = f2bf(lov);
      }
  }
  __syncthreads();

  {
    f32x4 acc = (f32x4){b3v,b3v,b3v,b3v};
    int arow = w*16 + ln;
#pragma unroll
    for (int ks=0;ks<2;ks++){
      int byt = arow*128 + ((ks*64 + q*16) ^ SWZ(arow));
      bfrag Ah = *(const bfrag*)((char*)e2h + byt);
      bfrag Al = *(const bfrag*)((char*)e2l + byt);
      acc = __builtin_amdgcn_mfma_f32_16x16x32_bf16(Ah, w3f[ks], acc, 0,0,0);
      acc = __builtin_amdgcn_mfma_f32_16x16x32_bf16(Al, w3f[ks], acc, 0,0,0);
    }
    if (ln < 2){
#pragma unroll
      for (int r=0;r<4;r++){
        int row = w*16 + q*4 + r;
        out[(e0 + row)*2 + ln] = acc[r];
      }
    }
  }
}

extern "C" void kernel_launch(void* const* d_in, const int* in_sizes, int n_in,
                              void* d_out, int out_size, void* d_ws, size_t ws_size,
                              hipStream_t stream) {
  const float* x    = (const float*)d_in[0];
  const int*   eidx = (const int*)  d_in[1];
  const float* eatt = (const float*)d_in[2];
  const float* Wih  = (const float*)d_in[3];
  const float* Whh  = (const float*)d_in[4];
  const float* bih  = (const float*)d_in[5];
  const float* bhh  = (const float*)d_in[6];
  const float* WlL  = (const float*)d_in[7];
  const float* blL  = (const float*)d_in[8];
  const float* WrL  = (const float*)d_in[9];
  const float* W1   = (const float*)d_in[10];
  const float* b1   = (const float*)d_in[11];
  const float* W2   = (const float*)d_in[12];
  const float* b2   = (const float*)d_in[13];
  const float* W3   = (const float*)d_in[14];
  const float* b3   = (const float*)d_in[15];
  const int*   src  = eidx;

  char* p = (char*)d_ws;
  unsigned short* HsHdB = (unsigned short*)p;   // [NN][256] bf16
  p += (size_t)NN*512*2;
  unsigned short* xb   = (unsigned short*)p; p += (size_t)NN*128*2;
  unsigned short* hb1  = (unsigned short*)p; p += (size_t)NN*128*2;
  unsigned short* hb2  = (unsigned short*)p; p += (size_t)NN*128*2;
  unsigned short* Wpck = (unsigned short*)p; p += (size_t)3*512*256*2;
  float* bspck         = (float*)p;          p += (size_t)3*512*4;
  unsigned short* Wlb  = (unsigned short*)p; p += (size_t)3*128*128*2;
  unsigned short* Wrb  = (unsigned short*)p; p += (size_t)3*128*128*2;
  unsigned short* W1nb = (unsigned short*)p; p += (size_t)256*128*2;
  unsigned short* W1eh = (unsigned short*)p; p += 2048*2;
  unsigned short* W1el = (unsigned short*)p; p += 2048*2;
  unsigned short* W2h  = (unsigned short*)p; p += 8192*2;
  unsigned short* W2l  = (unsigned short*)p; p += 8192*2;
  unsigned short* W3p  = (unsigned short*)p; p += 1024*2;

  dim3 blk(256);
  const int nb = (NN + 63)/64;

  k_cvt<<<(NN*128+255)/256, blk, 0, stream>>>(x, xb, NN*128);
  k_prep_all<<<(537088+255)/256, blk, 0, stream>>>(Wih, Whh, bih, bhh, WlL, WrL, W1, W2, W3,
                                                   Wpck, bspck, Wlb, Wrb, W1nb,
                                                   W1eh, W1el, W2h, W2l, W3p);

  const unsigned short* hin = xb;
  unsigned short* houts[3] = {hb1, hb2, hb1};
  for (int l = 0; l < 3; l++){
    k_lstm12<<<dim3(nb),dim3(1024),0,stream>>>(hin, src,
        Wpck + (size_t)l*512*256, bspck + (size_t)l*512,
        Wlb + (size_t)l*128*128, Wrb + (size_t)l*128*128, blL + (size_t)l*128,
        houts[l], NN);
    hin = houts[l];
  }
  k_bgemm<<<dim3(nb,2),blk,0,stream>>>(hin, nullptr, W1nb, nullptr,
                                       nullptr, nullptr, nullptr, HsHdB, 256, 0, NN);
  k_edge4<<<dim3(NN/4),blk,0,stream>>>(HsHdB, eatt, src, W1eh, W1el, W2h, W2l, W3p,
                                       b1, b2, b3, (float*)d_out);
}

// Round 15
// 1300.721 us; speedup vs baseline: 1.1000x; 1.1000x over previous
//
#include <hip/hip_runtime.h>
#include <hip/hip_bf16.h>

#define NN 50000
#define DEG 16

typedef __attribute__((ext_vector_type(8))) short bfrag;   // 8 x bf16 bits (16B)
typedef __attribute__((ext_vector_type(4))) float f32x4;

__device__ __forceinline__ float bf2f(unsigned int u){ return __uint_as_float(u<<16); }
__device__ __forceinline__ unsigned short f2bf(float x){
  unsigned int u = __float_as_uint(x);
  unsigned int r = (u + 0x7fffu + ((u>>16)&1u)) >> 16;
  return (unsigned short)r;
}
__device__ __forceinline__ float fast_rcp(float x){ return __builtin_amdgcn_rcpf(x); }
__device__ __forceinline__ float sigmoidf_(float x){ return fast_rcp(1.f + __expf(-x)); }
__device__ __forceinline__ float tanh_fast(float x){
  float e = __expf(-2.f*fabsf(x));
  float r = (1.f - e)*fast_rcp(1.f + e);
  return copysignf(r, x);
}
__device__ __forceinline__ float clamp10(float x){ return fminf(10.f, fmaxf(-10.f, x)); }

// Shared-rcp LSTM activation: 5 exp + 2 rcp (vs 10 trans).
// cn = sig(f)*c + sig(i)*tanh(g); h = sig(o)*tanh(cn).
__device__ __forceinline__ void lstm_act(float iv, float fv, float gg, float ov,
                                         float& c, float& h){
  float fi = clamp10(iv), ff = clamp10(fv), fg = clamp10(gg), fo = clamp10(ov);
  float ef = __expf(-ff), ei = __expf(-fi), eg = __expf(-2.f*fg);
  float D1 = 1.f + ef, D2 = 1.f + ei, D3 = 1.f + eg;
  float D23 = D2*D3;
  float R  = fast_rcp(D1*D23);
  float cn = R*(c*D23 + (1.f - eg)*D1);
  c = cn;
  float eo = __expf(-fo), ec = __expf(-2.f*cn);
  float R2 = fast_rcp((1.f + eo)*(1.f + ec));
  h = (1.f - ec)*R2;
}

#define SWZ(row) (((((row) ^ ((row)>>3)) & 7)) << 4)
// 4-bit slot swizzle for 256B rows (16 x 16B slots): final_slot = slot ^ (row&15)
#define SW4(row) (((row) & 15) << 4)

// global->LDS DMA, 16B per lane; LDS dest is wave-uniform base + lane*16 (linear).
#define GLDS16(g, l) __builtin_amdgcn_global_load_lds( \
    (const __attribute__((address_space(1))) unsigned int*)(g), \
    (__attribute__((address_space(3))) unsigned int*)(l), 16, 0, 0)

__global__ void k_cvt(const float* __restrict__ in, unsigned short* __restrict__ out, int n){
  int i = blockIdx.x*256 + threadIdx.x;
  if (i < n) out[i] = f2bf(in[i]);
}

// ONE prep kernel for all weight conversions.
__global__ void k_prep_all(const float* __restrict__ Wih, const float* __restrict__ Whh,
                           const float* __restrict__ bih, const float* __restrict__ bhh,
                           const float* __restrict__ WlL, const float* __restrict__ WrL,
                           const float* __restrict__ W1,  const float* __restrict__ W2,
                           const float* __restrict__ W3,
                           unsigned short* __restrict__ Wcat, float* __restrict__ bsum,
                           unsigned short* __restrict__ Wlb,  unsigned short* __restrict__ Wrb,
                           unsigned short* __restrict__ W1nb,
                           unsigned short* __restrict__ W1eh, unsigned short* __restrict__ W1el,
                           unsigned short* __restrict__ W2h,  unsigned short* __restrict__ W2l,
                           unsigned short* __restrict__ W3p)
{
  int i = blockIdx.x*256 + threadIdx.x;
  if (i < 393216){                       // Wcat[l][512][256] = [Wih|Whh]
    int l = i >> 17;
    int rem = i & 131071;
    int row = rem >> 8, col = rem & 255;
    float v = (col < 128) ? Wih[((size_t)l*512 + row)*128 + col]
                          : Whh[((size_t)l*512 + row)*128 + (col-128)];
    Wcat[i] = f2bf(v);
  } else if (i < 394752){                // bsum = bih + bhh
    int k = i - 393216;
    bsum[k] = bih[k] + bhh[k];
  } else if (i < 443904){                // Wlb
    int k = i - 394752;
    Wlb[k] = f2bf(WlL[k]);
  } else if (i < 493056){                // Wrb
    int k = i - 443904;
    Wrb[k] = f2bf(WrL[k]);
  } else if (i < 509440){                // W1nb rows 0..127 = W1[:, :128]
    int k = i - 493056; int r = k >> 7, c = k & 127;
    W1nb[k] = f2bf(W1[(size_t)r*272 + c]);
  } else if (i < 525824){                // W1nb rows 128..255 = W1[:, 128:256]
    int k = i - 509440; int r = k >> 7, c = k & 127;
    W1nb[16384 + k] = f2bf(W1[(size_t)r*272 + 128 + c]);
  } else if (i < 534016){                // W2 hi/lo
    int k = i - 525824;
    float v = W2[k];
    unsigned short hi = f2bf(v);
    W2h[k] = hi; W2l[k] = f2bf(v - bf2f(hi));
  } else if (i < 536064){                // W1e hi/lo (transposed [128][16])
    int k = i - 534016; int j = k >> 4, kk = k & 15;
    float v = W1[(size_t)j*272 + 256 + kk];
    unsigned short hi = f2bf(v);
    W1eh[k] = hi; W1el[k] = f2bf(v - bf2f(hi));
  } else if (i < 537088){                // W3 zero-padded [16][64]
    int k = i - 536064; int nr = k >> 6, c = k & 63;
    W3p[k] = f2bf(nr < 2 ? W3[nr*64 + c] : 0.f);
  }
}

// bf16 MFMA gemm (used for HsHd precompute, bf16 out).
__global__ __launch_bounds__(256,4) void k_bgemm(
    const unsigned short* __restrict__ Ab, const unsigned short* __restrict__ A2b,
    const unsigned short* __restrict__ Wb, const unsigned short* __restrict__ W2b,
    const float* __restrict__ bias, const float* __restrict__ bias2,
    float* __restrict__ outF, unsigned short* __restrict__ outB,
    int ostride, int dorelu, int n)
{
  const int t  = threadIdx.x;
  const int w  = t >> 6;
  const int l  = t & 63;
  const int ln = l & 15, q = l >> 4;
  const int n0 = blockIdx.x*64;
  const int j0 = blockIdx.y*128 + w*32;

  int nodeM[4];
#pragma unroll
  for (int mt=0;mt<4;mt++){ int nd = n0 + mt*16 + ln; nodeM[mt] = nd < n ? nd : n-1; }

  f32x4 acc[4][2];
#pragma unroll
  for (int mt=0;mt<4;mt++)
#pragma unroll
    for (int nt=0;nt<2;nt++) acc[mt][nt] = (f32x4){0.f,0.f,0.f,0.f};

  auto pass = [&](const unsigned short* __restrict__ Ap, const unsigned short* __restrict__ Wp){
#pragma unroll
    for (int ks=0;ks<4;ks++){
      bfrag Af[4], Bf[2];
#pragma unroll
      for (int mt=0;mt<4;mt++)
        Af[mt] = *(const bfrag*)(Ap + (size_t)nodeM[mt]*128 + ks*32 + q*8);
#pragma unroll
      for (int nt=0;nt<2;nt++)
        Bf[nt] = *(const bfrag*)(Wp + (size_t)(j0 + nt*16 + ln)*128 + ks*32 + q*8);
#pragma unroll
      for (int mt=0;mt<4;mt++)
#pragma unroll
        for (int nt=0;nt<2;nt++)
          acc[mt][nt] = __builtin_amdgcn_mfma_f32_16x16x32_bf16(Af[mt], Bf[nt], acc[mt][nt], 0,0,0);
    }
  };
  pass(Ab, Wb);
  if (A2b) pass(A2b, W2b);

#pragma unroll
  for (int nt=0;nt<2;nt++){
    int j = j0 + nt*16 + ln;
    float bv = bias ? bias[j] : 0.f;
    if (bias2) bv += bias2[j];
#pragma unroll
    for (int mt=0;mt<4;mt++)
#pragma unroll
      for (int r=0;r<4;r++){
        int row = n0 + mt*16 + q*4 + r;
        if (row < n){
          float v = acc[mt][nt][r] + bv;
          if (dorelu) v = fmaxf(v, 0.f);
          if (outF) outF[(size_t)row*ostride + j] = v;
          if (outB) outB[(size_t)row*ostride + j] = f2bf(v);
        }
      }
  }
}

// MFMA LSTM v13: R13's k_lstm9 with the shared-rcp activation (7 trans/elem vs 10).
// Everything else identical: x-gather K=256, SW4 swizzle, fused lin epilogue.
__global__ __launch_bounds__(512,2) void k_lstm13(
    const unsigned short* __restrict__ xin,  // [n][128] bf16 layer input
    const int* __restrict__ src,             // [n*16]
    const unsigned short* __restrict__ Wcat, // [512][256] bf16 ([Wih|Whh])
    const float* __restrict__ bsum,          // [512] bih+bhh
    const unsigned short* __restrict__ Wlb,  // [128][128] bf16 lin_l
    const unsigned short* __restrict__ Wrb,  // [128][128] bf16 lin_r
    const float* __restrict__ bl,            // [128]
    unsigned short* __restrict__ hout,       // [n][128] bf16 layer output
    int n)
{
  __shared__ unsigned short hs[64*128];        // 16 KB, row=node (256B), SW4
  __shared__ unsigned short xbuf[2][64*128];   // 2 x 16 KB, SW4
  __shared__ int srcs[64*16];                  // 4 KB
  const int t  = threadIdx.x;
  const int w  = t >> 6;                       // 0..7 hidden slice
  const int l  = t & 63;
  const int ln = l & 15;
  const int q  = l >> 4;
  const int n0 = blockIdx.x * 64;

  for (int i = t; i < 1024; i += 512){
    int nl = i >> 4, st = i & 15;
    srcs[i] = (n0+nl < n) ? src[(size_t)(n0+nl)*16 + st] : 0;
  }

  bfrag A[4][8];
#pragma unroll
  for (int T=0;T<4;T++)
#pragma unroll
    for (int ks=0;ks<8;ks++)
      A[T][ks] = *(const bfrag*)(Wcat + (size_t)(T*128 + w*16 + ln)*256 + ks*32 + q*8);

  f32x4 bsv[4];
#pragma unroll
  for (int T=0;T<4;T++)
    bsv[T] = *(const f32x4*)(bsum + T*128 + w*16 + q*4);

  float c[4][4];
#pragma unroll
  for (int nt=0;nt<4;nt++)
#pragma unroll
    for (int r=0;r<4;r++) c[nt][r]=0.f;

  __syncthreads();   // srcs visible

  auto stageX = [&](int step, int buf){
#pragma unroll
    for (int j=0;j<2;j++){
      int row  = w*8 + j*4 + (l>>4);
      int node = srcs[row*16 + step];
      const char* gsrc = (const char*)xin + (size_t)node*256 + (((l&15)*16) ^ SW4(row));
      char* ldst = (char*)&xbuf[buf][0] + (w*8 + j*4)*256;   // wave-uniform base
      GLDS16(gsrc, ldst);
    }
  };

  stageX(0, 0);
  asm volatile("s_waitcnt vmcnt(0)" ::: "memory");
  __syncthreads();

  for (int step=0; step<16; step++){
    const int cur = step & 1;
    if (step < 15) stageX(step+1, cur^1);

#pragma unroll
    for (int p=0;p<2;p++){
      f32x4 acc[4][2];  // [T][ntl]
#pragma unroll
      for (int T=0;T<4;T++)
#pragma unroll
        for (int ntl=0;ntl<2;ntl++) acc[T][ntl] = (f32x4){0.f,0.f,0.f,0.f};

#pragma unroll
      for (int ntl=0; ntl<2; ntl++){
        int node = p*32 + ntl*16 + ln;
        int swz  = SW4(node);
#pragma unroll
        for (int ks=0;ks<4;ks++){
          bfrag Bk = *(const bfrag*)((const char*)&xbuf[cur][0] + node*256 +
                       ((ks*64 + q*16) ^ swz));
#pragma unroll
          for (int T=0;T<4;T++)
            acc[T][ntl] = __builtin_amdgcn_mfma_f32_16x16x32_bf16(A[T][ks], Bk, acc[T][ntl], 0,0,0);
        }
        if (step > 0){
#pragma unroll
          for (int ks=4;ks<8;ks++){
            bfrag Bk = *(const bfrag*)((const char*)hs + node*256 +
                         (((ks-4)*64 + q*16) ^ swz));
#pragma unroll
            for (int T=0;T<4;T++)
              acc[T][ntl] = __builtin_amdgcn_mfma_f32_16x16x32_bf16(A[T][ks], Bk, acc[T][ntl], 0,0,0);
          }
        }
      }

      if (p == 1){
        asm volatile("s_waitcnt vmcnt(0)" ::: "memory");
      }
      __syncthreads();  // reads of rows [p*32,p*32+32) done before overwrite

#pragma unroll
      for (int ntl=0; ntl<2; ntl++){
        int nt = p*2 + ntl;
        int node = p*32 + ntl*16 + ln;
        float h[4];
#pragma unroll
        for (int r=0;r<4;r++){
          float iv = acc[0][ntl][r] + bsv[0][r];
          float fv = acc[1][ntl][r] + bsv[1][r];
          float gg = acc[2][ntl][r] + bsv[2][r];
          float ov = acc[3][ntl][r] + bsv[3][r];
          lstm_act(iv, fv, gg, ov, c[nt][r], h[r]);
        }
        unsigned pk01, pk23;
        asm("v_cvt_pk_bf16_f32 %0, %1, %2" : "=v"(pk01) : "v"(h[0]), "v"(h[1]));
        asm("v_cvt_pk_bf16_f32 %0, %1, %2" : "=v"(pk23) : "v"(h[2]), "v"(h[3]));
        uint2 pv; pv.x = pk01; pv.y = pk23;
        *(uint2*)((char*)hs + node*256 + (((w*32 + q*8)) ^ SW4(node))) = pv;
      }
    }
  }

  // ---- fused epilogue: hout = relu(Wl·h + Wr·x_own + bl), D[j][node] ----
  __syncthreads();   // final hs writes visible
  {
    bfrag Al[4], Ar[4];
#pragma unroll
    for (int ks=0;ks<4;ks++){
      Al[ks] = *(const bfrag*)(Wlb + (size_t)(w*16+ln)*128 + ks*32 + q*8);
      Ar[ks] = *(const bfrag*)(Wrb + (size_t)(w*16+ln)*128 + ks*32 + q*8);
    }
    f32x4 blv = *(const f32x4*)(bl + w*16 + q*4);
#pragma unroll
    for (int nt=0; nt<4; nt++){
      int node = nt*16 + ln;
      int gn = (n0+node < n) ? (n0+node) : (n-1);
      f32x4 acc = (f32x4){0.f,0.f,0.f,0.f};
#pragma unroll
      for (int ks=0;ks<4;ks++){
        bfrag Bh = *(const bfrag*)((const char*)hs + node*256 +
                     ((ks*64 + q*16) ^ SW4(node)));
        bfrag Bx = *(const bfrag*)(xin + (size_t)gn*128 + ks*32 + q*8);
        acc = __builtin_amdgcn_mfma_f32_16x16x32_bf16(Al[ks], Bh, acc, 0,0,0);
        acc = __builtin_amdgcn_mfma_f32_16x16x32_bf16(Ar[ks], Bx, acc, 0,0,0);
      }
      float v0 = fmaxf(acc[0]+blv[0], 0.f), v1 = fmaxf(acc[1]+blv[1], 0.f);
      float v2 = fmaxf(acc[2]+blv[2], 0.f), v3 = fmaxf(acc[3]+blv[3], 0.f);
      unsigned pk01, pk23;
      asm("v_cvt_pk_bf16_f32 %0, %1, %2" : "=v"(pk01) : "v"(v0), "v"(v1));
      asm("v_cvt_pk_bf16_f32 %0, %1, %2" : "=v"(pk23) : "v"(v2), "v"(v3));
      if (n0+node < n){
        uint2 pv; pv.x = pk01; pv.y = pk23;
        *(uint2*)(hout + (size_t)(n0+node)*128 + w*16 + q*4) = pv;
      }
    }
  }
}

// Edge MLP v4: Hs/Hd gathered as BF16. Unchanged from R13.
__global__ __launch_bounds__(256,2) void k_edge4(
    const unsigned short* __restrict__ HsHd,
    const float* __restrict__ ea,
    const int* __restrict__ src,
    const unsigned short* __restrict__ W1eh, const unsigned short* __restrict__ W1el,
    const unsigned short* __restrict__ W2h,  const unsigned short* __restrict__ W2l,
    const unsigned short* __restrict__ W3p,
    const float* __restrict__ b1, const float* __restrict__ b2, const float* __restrict__ b3,
    float* __restrict__ out)
{
  __shared__ unsigned short out1h[64*128];
  __shared__ unsigned short out1l[64*128];
  __shared__ unsigned short e2h[64*64];
  __shared__ unsigned short e2l[64*64];
  __shared__ unsigned short ea2[64*56];

  const int t = threadIdx.x;
  const int w = t>>6, l = t&63, ln = l&15, q = l>>4;
  const int nblk = blockIdx.x;
  const size_t e0 = (size_t)nblk*64;

  int srcv[4];
#pragma unroll
  for (int r=0;r<4;r++) srcv[r] = src[e0 + w*16 + q*4 + r];

  unsigned short hsq[8][4];
#pragma unroll
  for (int nt=0;nt<8;nt++)
#pragma unroll
    for (int r=0;r<4;r++)
      hsq[nt][r] = HsHd[(size_t)srcv[r]*256 + nt*16 + ln];

  unsigned short hdq[8];
#pragma unroll
  for (int nt=0;nt<8;nt++)
    hdq[nt] = HsHd[((size_t)nblk*4 + w)*256 + 128 + nt*16 + ln];

  float b1v[8];
#pragma unroll
  for (int nt=0;nt<8;nt++) b1v[nt] = b1[nt*16 + ln];
  float b2v[4];
#pragma unroll
  for (int nt=0;nt<4;nt++) b2v[nt] = b2[nt*16 + ln];
  float b3v = (ln<2) ? b3[ln] : 0.f;

  bfrag w1h[8], w1l[8];
#pragma unroll
  for (int nt=0;nt<8;nt++){
    int j = nt*16 + ln;
    w1h[nt] = *(const bfrag*)(W1eh + (size_t)j*16 + (q&1)*8);
    w1l[nt] = *(const bfrag*)(W1el + (size_t)j*16 + (q&1)*8);
  }
  bfrag w3f[2];
#pragma unroll
  for (int ks=0;ks<2;ks++)
    w3f[ks] = *(const bfrag*)(W3p + (size_t)ln*64 + ks*32 + q*8);

  for (int i=t;i<1024;i+=256){
    int e=i>>4, k=i&15;
    float v = ea[(e0+e)*16 + k];
    unsigned short hi = f2bf(v);
    ea2[e*56 + k] = hi;
    ea2[e*56 + 16 + k] = f2bf(v - bf2f(hi));
  }
  __syncthreads();

  {
    bfrag Aea = *(const bfrag*)&ea2[(w*16+ln)*56 + q*8];
#pragma unroll
    for (int nt=0;nt<8;nt++){
      float hdv = bf2f((unsigned)hdq[nt]);
      f32x4 acc;
#pragma unroll
      for (int r=0;r<4;r++) acc[r] = b1v[nt] + hdv + bf2f((unsigned)hsq[nt][r]);
      acc = __builtin_amdgcn_mfma_f32_16x16x32_bf16(Aea, w1h[nt], acc, 0,0,0);
      acc = __builtin_amdgcn_mfma_f32_16x16x32_bf16(Aea, w1l[nt], acc, 0,0,0);
      int j = nt*16 + ln;
#pragma unroll
      for (int r=0;r<4;r++){
        int row = w*16 + q*4 + r;
        float v = fmaxf(acc[r], 0.f);
        unsigned short hi = f2bf(v);
        float lov = v - bf2f(hi);
        int byt = row*256 + ((j*2) ^ SWZ(row));
        *(unsigned short*)((char*)out1h + byt) = hi;
        *(unsigned short*)((char*)out1l + byt) = f2bf(lov);
      }
    }
  }
  __syncthreads();

  {
    f32x4 acc[4];
#pragma unroll
    for (int nt=0;nt<4;nt++) acc[nt] = (f32x4){b2v[nt],b2v[nt],b2v[nt],b2v[nt]};
    int arow = w*16 + ln;

    bfrag BhA[4], BlA[4], BhB[4], BlB[4];
#pragma unroll
    for (int nt=0;nt<4;nt++){
      int j = nt*16 + ln;
      BhA[nt] = *(const bfrag*)(W2h + (size_t)j*128 + q*8);
      BlA[nt] = *(const bfrag*)(W2l + (size_t)j*128 + q*8);
    }
#pragma unroll
    for (int ks=0;ks<4;ks++){
      if (ks < 3){
#pragma unroll
        for (int nt=0;nt<4;nt++){
          int j = nt*16 + ln;
          if ((ks&1)==0){
            BhB[nt] = *(const bfrag*)(W2h + (size_t)j*128 + (ks+1)*32 + q*8);
            BlB[nt] = *(const bfrag*)(W2l + (size_t)j*128 + (ks+1)*32 + q*8);
          } else {
            BhA[nt] = *(const bfrag*)(W2h + (size_t)j*128 + (ks+1)*32 + q*8);
            BlA[nt] = *(const bfrag*)(W2l + (size_t)j*128 + (ks+1)*32 + q*8);
          }
        }
      }
      int byt = arow*256 + ((ks*64 + q*16) ^ SWZ(arow));
      bfrag Ah = *(const bfrag*)((char*)out1h + byt);
      bfrag Al = *(const bfrag*)((char*)out1l + byt);
#pragma unroll
      for (int nt=0;nt<4;nt++){
        bfrag Bh = ((ks&1)==0) ? BhA[nt] : BhB[nt];
        bfrag Bl = ((ks&1)==0) ? BlA[nt] : BlB[nt];
        acc[nt] = __builtin_amdgcn_mfma_f32_16x16x32_bf16(Ah, Bh, acc[nt], 0,0,0);
        acc[nt] = __builtin_amdgcn_mfma_f32_16x16x32_bf16(Al, Bh, acc[nt], 0,0,0);
        acc[nt] = __builtin_amdgcn_mfma_f32_16x16x32_bf16(Ah, Bl, acc[nt], 0,0,0);
      }
    }
#pragma unroll
    for (int nt=0;nt<4;nt++)
#pragma unroll
      for (int r=0;r<4;r++){
        int row = w*16 + q*4 + r;
        int j = nt*16 + ln;
        float v = fmaxf(acc[nt][r], 0.f);
        unsigned short hi = f2bf(v);
        float lov = v - bf2f(hi);
        int byt = row*128 + ((j*2) ^ SWZ(row));
        *(unsigned short*)((char*)e2h + byt) = hi;
        *(unsigned short*)((char*)e2l + byt) = f2bf(lov);
      }
  }
  __syncthreads();

  {
    f32x4 acc = (f32x4){b3v,b3v,b3v,b3v};
    int arow = w*16 + ln;
#pragma unroll
    for (int ks=0;ks<2;ks++){
      int byt = arow*128 + ((ks*64 + q*16) ^ SWZ(arow));
      bfrag Ah = *(const bfrag*)((char*)e2h + byt);
      bfrag Al = *(const bfrag*)((char*)e2l + byt);
      acc = __builtin_amdgcn_mfma_f32_16x16x32_bf16(Ah, w3f[ks], acc, 0,0,0);
      acc = __builtin_amdgcn_mfma_f32_16x16x32_bf16(Al, w3f[ks], acc, 0,0,0);
    }
    if (ln < 2){
#pragma unroll
      for (int r=0;r<4;r++){
        int row = w*16 + q*4 + r;
        out[(e0 + row)*2 + ln] = acc[r];
      }
    }
  }
}

extern "C" void kernel_launch(void* const* d_in, const int* in_sizes, int n_in,
                              void* d_out, int out_size, void* d_ws, size_t ws_size,
                              hipStream_t stream) {
  const float* x    = (const float*)d_in[0];
  const int*   eidx = (const int*)  d_in[1];
  const float* eatt = (const float*)d_in[2];
  const float* Wih  = (const float*)d_in[3];
  const float* Whh  = (const float*)d_in[4];
  const float* bih  = (const float*)d_in[5];
  const float* bhh  = (const float*)d_in[6];
  const float* WlL  = (const float*)d_in[7];
  const float* blL  = (const float*)d_in[8];
  const float* WrL  = (const float*)d_in[9];
  const float* W1   = (const float*)d_in[10];
  const float* b1   = (const float*)d_in[11];
  const float* W2   = (const float*)d_in[12];
  const float* b2   = (const float*)d_in[13];
  const float* W3   = (const float*)d_in[14];
  const float* b3   = (const float*)d_in[15];
  const int*   src  = eidx;

  char* p = (char*)d_ws;
  unsigned short* HsHdB = (unsigned short*)p;   // [NN][256] bf16
  p += (size_t)NN*512*2;
  unsigned short* xb   = (unsigned short*)p; p += (size_t)NN*128*2;
  unsigned short* hb1  = (unsigned short*)p; p += (size_t)NN*128*2;
  unsigned short* hb2  = (unsigned short*)p; p += (size_t)NN*128*2;
  unsigned short* Wcat = (unsigned short*)p; p += (size_t)3*512*256*2;
  float* bsum          = (float*)p;          p += (size_t)3*512*4;
  unsigned short* Wlb  = (unsigned short*)p; p += (size_t)3*128*128*2;
  unsigned short* Wrb  = (unsigned short*)p; p += (size_t)3*128*128*2;
  unsigned short* W1nb = (unsigned short*)p; p += (size_t)256*128*2;
  unsigned short* W1eh = (unsigned short*)p; p += 2048*2;
  unsigned short* W1el = (unsigned short*)p; p += 2048*2;
  unsigned short* W2h  = (unsigned short*)p; p += 8192*2;
  unsigned short* W2l  = (unsigned short*)p; p += 8192*2;
  unsigned short* W3p  = (unsigned short*)p; p += 1024*2;

  dim3 blk(256);
  const int nb = (NN + 63)/64;

  k_cvt<<<(NN*128+255)/256, blk, 0, stream>>>(x, xb, NN*128);
  k_prep_all<<<(537088+255)/256, blk, 0, stream>>>(Wih, Whh, bih, bhh, WlL, WrL, W1, W2, W3,
                                                   Wcat, bsum, Wlb, Wrb, W1nb,
                                                   W1eh, W1el, W2h, W2l, W3p);

  const unsigned short* hin = xb;
  unsigned short* houts[3] = {hb1, hb2, hb1};
  for (int l = 0; l < 3; l++){
    k_lstm13<<<dim3(nb),dim3(512),0,stream>>>(hin, src,
        Wcat + (size_t)l*512*256, bsum + (size_t)l*512,
        Wlb + (size_t)l*128*128, Wrb + (size_t)l*128*128, blL + (size_t)l*128,
        houts[l], NN);
    hin = houts[l];
  }
  k_bgemm<<<dim3(nb,2),blk,0,stream>>>(hin, nullptr, W1nb, nullptr,
                                       nullptr, nullptr, nullptr, HsHdB, 256, 0, NN);
  k_edge4<<<dim3(NN/4),blk,0,stream>>>(HsHdB, eatt, src, W1eh, W1el, W2h, W2l, W3p,
                                       b1, b2, b3, (float*)d_out);
}

// Round 16
// 1173.799 us; speedup vs baseline: 1.2189x; 1.1081x over previous
//
#include <hip/hip_runtime.h>
#include <hip/hip_bf16.h>

#define NN 50000
#define DEG 16
// mixed grid: 53 blocks x 64 nodes + 971 blocks x 48 nodes = 1024 blocks = 4/CU
#define NBIG 53
#define NBLK_TOTAL 1024

typedef __attribute__((ext_vector_type(8))) short bfrag;   // 8 x bf16 bits (16B)
typedef __attribute__((ext_vector_type(4))) float f32x4;

__device__ __forceinline__ float bf2f(unsigned int u){ return __uint_as_float(u<<16); }
__device__ __forceinline__ unsigned short f2bf(float x){
  unsigned int u = __float_as_uint(x);
  unsigned int r = (u + 0x7fffu + ((u>>16)&1u)) >> 16;
  return (unsigned short)r;
}
__device__ __forceinline__ float fast_rcp(float x){ return __builtin_amdgcn_rcpf(x); }
__device__ __forceinline__ float clamp10(float x){ return fminf(10.f, fmaxf(-10.f, x)); }

// Shared-rcp LSTM activation: 5 exp + 2 rcp (vs 10 trans).
__device__ __forceinline__ void lstm_act(float iv, float fv, float gg, float ov,
                                         float& c, float& h){
  float fi = clamp10(iv), ff = clamp10(fv), fg = clamp10(gg), fo = clamp10(ov);
  float ef = __expf(-ff), ei = __expf(-fi), eg = __expf(-2.f*fg);
  float D1 = 1.f + ef, D2 = 1.f + ei, D3 = 1.f + eg;
  float D23 = D2*D3;
  float R  = fast_rcp(D1*D23);
  float cn = R*(c*D23 + (1.f - eg)*D1);
  c = cn;
  float eo = __expf(-fo), ec = __expf(-2.f*cn);
  float R2 = fast_rcp((1.f + eo)*(1.f + ec));
  h = (1.f - ec)*R2;
}

#define SWZ(row) (((((row) ^ ((row)>>3)) & 7)) << 4)
#define SW4(row) (((row) & 15) << 4)

#define GLDS16(g, l) __builtin_amdgcn_global_load_lds( \
    (const __attribute__((address_space(1))) unsigned int*)(g), \
    (__attribute__((address_space(3))) unsigned int*)(l), 16, 0, 0)

__global__ void k_cvt(const float* __restrict__ in, unsigned short* __restrict__ out, int n){
  int i = blockIdx.x*256 + threadIdx.x;
  if (i < n) out[i] = f2bf(in[i]);
}

// ONE prep kernel for all weight conversions.
__global__ void k_prep_all(const float* __restrict__ Wih, const float* __restrict__ Whh,
                           const float* __restrict__ bih, const float* __restrict__ bhh,
                           const float* __restrict__ WlL, const float* __restrict__ WrL,
                           const float* __restrict__ W1,  const float* __restrict__ W2,
                           const float* __restrict__ W3,
                           unsigned short* __restrict__ Wcat, float* __restrict__ bsum,
                           unsigned short* __restrict__ Wlb,  unsigned short* __restrict__ Wrb,
                           unsigned short* __restrict__ W1nb,
                           unsigned short* __restrict__ W1eh, unsigned short* __restrict__ W1el,
                           unsigned short* __restrict__ W2h,  unsigned short* __restrict__ W2l,
                           unsigned short* __restrict__ W3p)
{
  int i = blockIdx.x*256 + threadIdx.x;
  if (i < 393216){
    int l = i >> 17;
    int rem = i & 131071;
    int row = rem >> 8, col = rem & 255;
    float v = (col < 128) ? Wih[((size_t)l*512 + row)*128 + col]
                          : Whh[((size_t)l*512 + row)*128 + (col-128)];
    Wcat[i] = f2bf(v);
  } else if (i < 394752){
    int k = i - 393216;
    bsum[k] = bih[k] + bhh[k];
  } else if (i < 443904){
    int k = i - 394752;
    Wlb[k] = f2bf(WlL[k]);
  } else if (i < 493056){
    int k = i - 443904;
    Wrb[k] = f2bf(WrL[k]);
  } else if (i < 509440){
    int k = i - 493056; int r = k >> 7, c = k & 127;
    W1nb[k] = f2bf(W1[(size_t)r*272 + c]);
  } else if (i < 525824){
    int k = i - 509440; int r = k >> 7, c = k & 127;
    W1nb[16384 + k] = f2bf(W1[(size_t)r*272 + 128 + c]);
  } else if (i < 534016){
    int k = i - 525824;
    float v = W2[k];
    unsigned short hi = f2bf(v);
    W2h[k] = hi; W2l[k] = f2bf(v - bf2f(hi));
  } else if (i < 536064){
    int k = i - 534016; int j = k >> 4, kk = k & 15;
    float v = W1[(size_t)j*272 + 256 + kk];
    unsigned short hi = f2bf(v);
    W1eh[k] = hi; W1el[k] = f2bf(v - bf2f(hi));
  } else if (i < 537088){
    int k = i - 536064; int nr = k >> 6, c = k & 63;
    W3p[k] = f2bf(nr < 2 ? W3[nr*64 + c] : 0.f);
  }
}

// bf16 MFMA gemm (HsHd precompute, bf16 out). Unchanged.
__global__ __launch_bounds__(256,4) void k_bgemm(
    const unsigned short* __restrict__ Ab, const unsigned short* __restrict__ A2b,
    const unsigned short* __restrict__ Wb, const unsigned short* __restrict__ W2b,
    const float* __restrict__ bias, const float* __restrict__ bias2,
    float* __restrict__ outF, unsigned short* __restrict__ outB,
    int ostride, int dorelu, int n)
{
  const int t  = threadIdx.x;
  const int w  = t >> 6;
  const int l  = t & 63;
  const int ln = l & 15, q = l >> 4;
  const int n0 = blockIdx.x*64;
  const int j0 = blockIdx.y*128 + w*32;

  int nodeM[4];
#pragma unroll
  for (int mt=0;mt<4;mt++){ int nd = n0 + mt*16 + ln; nodeM[mt] = nd < n ? nd : n-1; }

  f32x4 acc[4][2];
#pragma unroll
  for (int mt=0;mt<4;mt++)
#pragma unroll
    for (int nt=0;nt<2;nt++) acc[mt][nt] = (f32x4){0.f,0.f,0.f,0.f};

  auto pass = [&](const unsigned short* __restrict__ Ap, const unsigned short* __restrict__ Wp){
#pragma unroll
    for (int ks=0;ks<4;ks++){
      bfrag Af[4], Bf[2];
#pragma unroll
      for (int mt=0;mt<4;mt++)
        Af[mt] = *(const bfrag*)(Ap + (size_t)nodeM[mt]*128 + ks*32 + q*8);
#pragma unroll
      for (int nt=0;nt<2;nt++)
        Bf[nt] = *(const bfrag*)(Wp + (size_t)(j0 + nt*16 + ln)*128 + ks*32 + q*8);
#pragma unroll
      for (int mt=0;mt<4;mt++)
#pragma unroll
        for (int nt=0;nt<2;nt++)
          acc[mt][nt] = __builtin_amdgcn_mfma_f32_16x16x32_bf16(Af[mt], Bf[nt], acc[mt][nt], 0,0,0);
    }
  };
  pass(Ab, Wb);
  if (A2b) pass(A2b, W2b);

#pragma unroll
  for (int nt=0;nt<2;nt++){
    int j = j0 + nt*16 + ln;
    float bv = bias ? bias[j] : 0.f;
    if (bias2) bv += bias2[j];
#pragma unroll
    for (int mt=0;mt<4;mt++)
#pragma unroll
      for (int r=0;r<4;r++){
        int row = n0 + mt*16 + q*4 + r;
        if (row < n){
          float v = acc[mt][nt][r] + bv;
          if (dorelu) v = fmaxf(v, 0.f);
          if (outF) outF[(size_t)row*ostride + j] = v;
          if (outB) outB[(size_t)row*ostride + j] = f2bf(v);
        }
      }
  }
}

// MFMA LSTM v14: R15's k_lstm13 + mixed-size grid load balancing.
// 1024 blocks = exactly 4/CU: blocks [0,53) do 64 nodes, [53,1024) do 48 nodes.
__global__ __launch_bounds__(512,2) void k_lstm14(
    const unsigned short* __restrict__ xin,  // [n][128] bf16 layer input
    const int* __restrict__ src,             // [n*16]
    const unsigned short* __restrict__ Wcat, // [512][256] bf16 ([Wih|Whh])
    const float* __restrict__ bsum,          // [512] bih+bhh
    const unsigned short* __restrict__ Wlb,  // [128][128] bf16 lin_l
    const unsigned short* __restrict__ Wrb,  // [128][128] bf16 lin_r
    const float* __restrict__ bl,            // [128]
    unsigned short* __restrict__ hout,       // [n][128] bf16 layer output
    int n)
{
  __shared__ unsigned short hs[64*128];        // 16 KB, row=node (256B), SW4
  __shared__ unsigned short xbuf[2][64*128];   // 2 x 16 KB, SW4
  __shared__ int srcs[64*16];                  // 4 KB
  const int t  = threadIdx.x;
  const int w  = t >> 6;                       // 0..7 hidden slice
  const int l  = t & 63;
  const int ln = l & 15;
  const int q  = l >> 4;

  const int nblk = blockIdx.x;
  int n0, NTI;                                 // NTI = #16-node tiles (4 or 3)
  if (nblk < NBIG){ n0 = nblk*64; NTI = 4; }
  else            { n0 = NBIG*64 + (nblk - NBIG)*48; NTI = 3; }

  for (int i = t; i < 1024; i += 512){
    int nl = i >> 4, st = i & 15;
    srcs[i] = (n0+nl < n) ? src[(size_t)(n0+nl)*16 + st] : 0;
  }

  bfrag A[4][8];
#pragma unroll
  for (int T=0;T<4;T++)
#pragma unroll
    for (int ks=0;ks<8;ks++)
      A[T][ks] = *(const bfrag*)(Wcat + (size_t)(T*128 + w*16 + ln)*256 + ks*32 + q*8);

  f32x4 bsv[4];
#pragma unroll
  for (int T=0;T<4;T++)
    bsv[T] = *(const f32x4*)(bsum + T*128 + w*16 + q*4);

  float c[4][4];
#pragma unroll
  for (int nt=0;nt<4;nt++)
#pragma unroll
    for (int r=0;r<4;r++) c[nt][r]=0.f;

  __syncthreads();   // srcs visible

  auto stageX = [&](int step, int buf){
#pragma unroll
    for (int j=0;j<2;j++){
      int row  = w*8 + j*4 + (l>>4);
      if (row < NTI*16){
        int node = srcs[row*16 + step];
        const char* gsrc = (const char*)xin + (size_t)node*256 + (((l&15)*16) ^ SW4(row));
        char* ldst = (char*)&xbuf[buf][0] + (w*8 + j*4)*256;   // wave-uniform base
        GLDS16(gsrc, ldst);
      }
    }
  };

  stageX(0, 0);
  asm volatile("s_waitcnt vmcnt(0)" ::: "memory");
  __syncthreads();

  for (int step=0; step<16; step++){
    const int cur = step & 1;
    if (step < 15) stageX(step+1, cur^1);

#pragma unroll
    for (int p=0;p<2;p++){
      f32x4 acc[4][2];  // [T][ntl]
#pragma unroll
      for (int T=0;T<4;T++)
#pragma unroll
        for (int ntl=0;ntl<2;ntl++) acc[T][ntl] = (f32x4){0.f,0.f,0.f,0.f};

#pragma unroll
      for (int ntl=0; ntl<2; ntl++){
        if (p*2 + ntl < NTI){
          int node = p*32 + ntl*16 + ln;
          int swz  = SW4(node);
#pragma unroll
          for (int ks=0;ks<4;ks++){
            bfrag Bk = *(const bfrag*)((const char*)&xbuf[cur][0] + node*256 +
                         ((ks*64 + q*16) ^ swz));
#pragma unroll
            for (int T=0;T<4;T++)
              acc[T][ntl] = __builtin_amdgcn_mfma_f32_16x16x32_bf16(A[T][ks], Bk, acc[T][ntl], 0,0,0);
          }
          if (step > 0){
#pragma unroll
            for (int ks=4;ks<8;ks++){
              bfrag Bk = *(const bfrag*)((const char*)hs + node*256 +
                           (((ks-4)*64 + q*16) ^ swz));
#pragma unroll
              for (int T=0;T<4;T++)
                acc[T][ntl] = __builtin_amdgcn_mfma_f32_16x16x32_bf16(A[T][ks], Bk, acc[T][ntl], 0,0,0);
            }
          }
        }
      }

      if (p == 1){
        asm volatile("s_waitcnt vmcnt(0)" ::: "memory");
      }
      __syncthreads();  // reads of rows [p*32,p*32+32) done before overwrite

#pragma unroll
      for (int ntl=0; ntl<2; ntl++){
        if (p*2 + ntl < NTI){
          int nt = p*2 + ntl;
          int node = p*32 + ntl*16 + ln;
          float h[4];
#pragma unroll
          for (int r=0;r<4;r++){
            float iv = acc[0][ntl][r] + bsv[0][r];
            float fv = acc[1][ntl][r] + bsv[1][r];
            float gg = acc[2][ntl][r] + bsv[2][r];
            float ov = acc[3][ntl][r] + bsv[3][r];
            lstm_act(iv, fv, gg, ov, c[nt][r], h[r]);
          }
          unsigned pk01, pk23;
          asm("v_cvt_pk_bf16_f32 %0, %1, %2" : "=v"(pk01) : "v"(h[0]), "v"(h[1]));
          asm("v_cvt_pk_bf16_f32 %0, %1, %2" : "=v"(pk23) : "v"(h[2]), "v"(h[3]));
          uint2 pv; pv.x = pk01; pv.y = pk23;
          *(uint2*)((char*)hs + node*256 + (((w*32 + q*8)) ^ SW4(node))) = pv;
        }
      }
    }
  }

  // ---- fused epilogue: hout = relu(Wl·h + Wr·x_own + bl) ----
  __syncthreads();   // final hs writes visible
  {
    bfrag Al[4], Ar[4];
#pragma unroll
    for (int ks=0;ks<4;ks++){
      Al[ks] = *(const bfrag*)(Wlb + (size_t)(w*16+ln)*128 + ks*32 + q*8);
      Ar[ks] = *(const bfrag*)(Wrb + (size_t)(w*16+ln)*128 + ks*32 + q*8);
    }
    f32x4 blv = *(const f32x4*)(bl + w*16 + q*4);
#pragma unroll
    for (int nt=0; nt<4; nt++){
      if (nt < NTI){
        int node = nt*16 + ln;
        int gn = (n0+node < n) ? (n0+node) : (n-1);
        f32x4 acc = (f32x4){0.f,0.f,0.f,0.f};
#pragma unroll
        for (int ks=0;ks<4;ks++){
          bfrag Bh = *(const bfrag*)((const char*)hs + node*256 +
                       ((ks*64 + q*16) ^ SW4(node)));
          bfrag Bx = *(const bfrag*)(xin + (size_t)gn*128 + ks*32 + q*8);
          acc = __builtin_amdgcn_mfma_f32_16x16x32_bf16(Al[ks], Bh, acc, 0,0,0);
          acc = __builtin_amdgcn_mfma_f32_16x16x32_bf16(Ar[ks], Bx, acc, 0,0,0);
        }
        float v0 = fmaxf(acc[0]+blv[0], 0.f), v1 = fmaxf(acc[1]+blv[1], 0.f);
        float v2 = fmaxf(acc[2]+blv[2], 0.f), v3 = fmaxf(acc[3]+blv[3], 0.f);
        unsigned pk01, pk23;
        asm("v_cvt_pk_bf16_f32 %0, %1, %2" : "=v"(pk01) : "v"(v0), "v"(v1));
        asm("v_cvt_pk_bf16_f32 %0, %1, %2" : "=v"(pk23) : "v"(v2), "v"(v3));
        if (n0+node < n){
          uint2 pv; pv.x = pk01; pv.y = pk23;
          *(uint2*)(hout + (size_t)(n0+node)*128 + w*16 + q*4) = pv;
        }
      }
    }
  }
}

// Edge MLP v4: Hs/Hd gathered as BF16. Unchanged from R13/R15.
__global__ __launch_bounds__(256,2) void k_edge4(
    const unsigned short* __restrict__ HsHd,
    const float* __restrict__ ea,
    const int* __restrict__ src,
    const unsigned short* __restrict__ W1eh, const unsigned short* __restrict__ W1el,
    const unsigned short* __restrict__ W2h,  const unsigned short* __restrict__ W2l,
    const unsigned short* __restrict__ W3p,
    const float* __restrict__ b1, const float* __restrict__ b2, const float* __restrict__ b3,
    float* __restrict__ out)
{
  __shared__ unsigned short out1h[64*128];
  __shared__ unsigned short out1l[64*128];
  __shared__ unsigned short e2h[64*64];
  __shared__ unsigned short e2l[64*64];
  __shared__ unsigned short ea2[64*56];

  const int t = threadIdx.x;
  const int w = t>>6, l = t&63, ln = l&15, q = l>>4;
  const int nblk = blockIdx.x;
  const size_t e0 = (size_t)nblk*64;

  int srcv[4];
#pragma unroll
  for (int r=0;r<4;r++) srcv[r] = src[e0 + w*16 + q*4 + r];

  unsigned short hsq[8][4];
#pragma unroll
  for (int nt=0;nt<8;nt++)
#pragma unroll
    for (int r=0;r<4;r++)
      hsq[nt][r] = HsHd[(size_t)srcv[r]*256 + nt*16 + ln];

  unsigned short hdq[8];
#pragma unroll
  for (int nt=0;nt<8;nt++)
    hdq[nt] = HsHd[((size_t)nblk*4 + w)*256 + 128 + nt*16 + ln];

  float b1v[8];
#pragma unroll
  for (int nt=0;nt<8;nt++) b1v[nt] = b1[nt*16 + ln];
  float b2v[4];
#pragma unroll
  for (int nt=0;nt<4;nt++) b2v[nt] = b2[nt*16 + ln];
  float b3v = (ln<2) ? b3[ln] : 0.f;

  bfrag w1h[8], w1l[8];
#pragma unroll
  for (int nt=0;nt<8;nt++){
    int j = nt*16 + ln;
    w1h[nt] = *(const bfrag*)(W1eh + (size_t)j*16 + (q&1)*8);
    w1l[nt] = *(const bfrag*)(W1el + (size_t)j*16 + (q&1)*8);
  }
  bfrag w3f[2];
#pragma unroll
  for (int ks=0;ks<2;ks++)
    w3f[ks] = *(const bfrag*)(W3p + (size_t)ln*64 + ks*32 + q*8);

  for (int i=t;i<1024;i+=256){
    int e=i>>4, k=i&15;
    float v = ea[(e0+e)*16 + k];
    unsigned short hi = f2bf(v);
    ea2[e*56 + k] = hi;
    ea2[e*56 + 16 + k] = f2bf(v - bf2f(hi));
  }
  __syncthreads();

  {
    bfrag Aea = *(const bfrag*)&ea2[(w*16+ln)*56 + q*8];
#pragma unroll
    for (int nt=0;nt<8;nt++){
      float hdv = bf2f((unsigned)hdq[nt]);
      f32x4 acc;
#pragma unroll
      for (int r=0;r<4;r++) acc[r] = b1v[nt] + hdv + bf2f((unsigned)hsq[nt][r]);
      acc = __builtin_amdgcn_mfma_f32_16x16x32_bf16(Aea, w1h[nt], acc, 0,0,0);
      acc = __builtin_amdgcn_mfma_f32_16x16x32_bf16(Aea, w1l[nt], acc, 0,0,0);
      int j = nt*16 + ln;
#pragma unroll
      for (int r=0;r<4;r++){
        int row = w*16 + q*4 + r;
        float v = fmaxf(acc[r], 0.f);
        unsigned short hi = f2bf(v);
        float lov = v - bf2f(hi);
        int byt = row*256 + ((j*2) ^ SWZ(row));
        *(unsigned short*)((char*)out1h + byt) = hi;
        *(unsigned short*)((char*)out1l + byt) = f2bf(lov);
      }
    }
  }
  __syncthreads();

  {
    f32x4 acc[4];
#pragma unroll
    for (int nt=0;nt<4;nt++) acc[nt] = (f32x4){b2v[nt],b2v[nt],b2v[nt],b2v[nt]};
    int arow = w*16 + ln;

    bfrag BhA[4], BlA[4], BhB[4], BlB[4];
#pragma unroll
    for (int nt=0;nt<4;nt++){
      int j = nt*16 + ln;
      BhA[nt] = *(const bfrag*)(W2h + (size_t)j*128 + q*8);
      BlA[nt] = *(const bfrag*)(W2l + (size_t)j*128 + q*8);
    }
#pragma unroll
    for (int ks=0;ks<4;ks++){
      if (ks < 3){
#pragma unroll
        for (int nt=0;nt<4;nt++){
          int j = nt*16 + ln;
          if ((ks&1)==0){
            BhB[nt] = *(const bfrag*)(W2h + (size_t)j*128 + (ks+1)*32 + q*8);
            BlB[nt] = *(const bfrag*)(W2l + (size_t)j*128 + (ks+1)*32 + q*8);
          } else {
            BhA[nt] = *(const bfrag*)(W2h + (size_t)j*128 + (ks+1)*32 + q*8);
            BlA[nt] = *(const bfrag*)(W2l + (size_t)j*128 + (ks+1)*32 + q*8);
          }
        }
      }
      int byt = arow*256 + ((ks*64 + q*16) ^ SWZ(arow));
      bfrag Ah = *(const bfrag*)((char*)out1h + byt);
      bfrag Al = *(const bfrag*)((char*)out1l + byt);
#pragma unroll
      for (int nt=0;nt<4;nt++){
        bfrag Bh = ((ks&1)==0) ? BhA[nt] : BhB[nt];
        bfrag Bl = ((ks&1)==0) ? BlA[nt] : BlB[nt];
        acc[nt] = __builtin_amdgcn_mfma_f32_16x16x32_bf16(Ah, Bh, acc[nt], 0,0,0);
        acc[nt] = __builtin_amdgcn_mfma_f32_16x16x32_bf16(Al, Bh, acc[nt], 0,0,0);
        acc[nt] = __builtin_amdgcn_mfma_f32_16x16x32_bf16(Ah, Bl, acc[nt], 0,0,0);
      }
    }
#pragma unroll
    for (int nt=0;nt<4;nt++)
#pragma unroll
      for (int r=0;r<4;r++){
        int row = w*16 + q*4 + r;
        int j = nt*16 + ln;
        float v = fmaxf(acc[nt][r], 0.f);
        unsigned short hi = f2bf(v);
        float lov = v - bf2f(hi);
        int byt = row*128 + ((j*2) ^ SWZ(row));
        *(unsigned short*)((char*)e2h + byt) = hi;
        *(unsigned short*)((char*)e2l + byt) = f2bf(lov);
      }
  }
  __syncthreads();

  {
    f32x4 acc = (f32x4){b3v,b3v,b3v,b3v};
    int arow = w*16 + ln;
#pragma unroll
    for (int ks=0;ks<2;ks++){
      int byt = arow*128 + ((ks*64 + q*16) ^ SWZ(arow));
      bfrag Ah = *(const bfrag*)((char*)e2h + byt);
      bfrag Al = *(const bfrag*)((char*)e2l + byt);
      acc = __builtin_amdgcn_mfma_f32_16x16x32_bf16(Ah, w3f[ks], acc, 0,0,0);
      acc = __builtin_amdgcn_mfma_f32_16x16x32_bf16(Al, w3f[ks], acc, 0,0,0);
    }
    if (ln < 2){
#pragma unroll
      for (int r=0;r<4;r++){
        int row = w*16 + q*4 + r;
        out[(e0 + row)*2 + ln] = acc[r];
      }
    }
  }
}

extern "C" void kernel_launch(void* const* d_in, const int* in_sizes, int n_in,
                              void* d_out, int out_size, void* d_ws, size_t ws_size,
                              hipStream_t stream) {
  const float* x    = (const float*)d_in[0];
  const int*   eidx = (const int*)  d_in[1];
  const float* eatt = (const float*)d_in[2];
  const float* Wih  = (const float*)d_in[3];
  const float* Whh  = (const float*)d_in[4];
  const float* bih  = (const float*)d_in[5];
  const float* bhh  = (const float*)d_in[6];
  const float* WlL  = (const float*)d_in[7];
  const float* blL  = (const float*)d_in[8];
  const float* WrL  = (const float*)d_in[9];
  const float* W1   = (const float*)d_in[10];
  const float* b1   = (const float*)d_in[11];
  const float* W2   = (const float*)d_in[12];
  const float* b2   = (const float*)d_in[13];
  const float* W3   = (const float*)d_in[14];
  const float* b3   = (const float*)d_in[15];
  const int*   src  = eidx;

  char* p = (char*)d_ws;
  unsigned short* HsHdB = (unsigned short*)p;   // [NN][256] bf16
  p += (size_t)NN*512*2;
  unsigned short* xb   = (unsigned short*)p; p += (size_t)NN*128*2;
  unsigned short* hb1  = (unsigned short*)p; p += (size_t)NN*128*2;
  unsigned short* hb2  = (unsigned short*)p; p += (size_t)NN*128*2;
  unsigned short* Wcat = (unsigned short*)p; p += (size_t)3*512*256*2;
  float* bsum          = (float*)p;          p += (size_t)3*512*4;
  unsigned short* Wlb  = (unsigned short*)p; p += (size_t)3*128*128*2;
  unsigned short* Wrb  = (unsigned short*)p; p += (size_t)3*128*128*2;
  unsigned short* W1nb = (unsigned short*)p; p += (size_t)256*128*2;
  unsigned short* W1eh = (unsigned short*)p; p += 2048*2;
  unsigned short* W1el = (unsigned short*)p; p += 2048*2;
  unsigned short* W2h  = (unsigned short*)p; p += 8192*2;
  unsigned short* W2l  = (unsigned short*)p; p += 8192*2;
  unsigned short* W3p  = (unsigned short*)p; p += 1024*2;

  dim3 blk(256);
  const int nb = (NN + 63)/64;

  k_cvt<<<(NN*128+255)/256, blk, 0, stream>>>(x, xb, NN*128);
  k_prep_all<<<(537088+255)/256, blk, 0, stream>>>(Wih, Whh, bih, bhh, WlL, WrL, W1, W2, W3,
                                                   Wcat, bsum, Wlb, Wrb, W1nb,
                                                   W1eh, W1el, W2h, W2l, W3p);

  const unsigned short* hin = xb;
  unsigned short* houts[3] = {hb1, hb2, hb1};
  for (int l = 0; l < 3; l++){
    k_lstm14<<<dim3(NBLK_TOTAL),dim3(512),0,stream>>>(hin, src,
        Wcat + (size_t)l*512*256, bsum + (size_t)l*512,
        Wlb + (size_t)l*128*128, Wrb + (size_t)l*128*128, blL + (size_t)l*128,
        houts[l], NN);
    hin = houts[l];
  }
  k_bgemm<<<dim3(nb,2),blk,0,stream>>>(hin, nullptr, W1nb, nullptr,
                                       nullptr, nullptr, nullptr, HsHdB, 256, 0, NN);
  k_edge4<<<dim3(NN/4),blk,0,stream>>>(HsHdB, eatt, src, W1eh, W1el, W2h, W2l, W3p,
                                       b1, b2, b3, (float*)d_out);
}